// Round 1
// baseline (3469.814 us; speedup 1.0000x reference)
//
#include <hip/hip_runtime.h>
#include <math.h>

#define BSZ 512
#define SEQ 128
#define FF  136
#define HH  128

// ---------------- transpose (384x128 -> 128x384) ----------------
__global__ __launch_bounds__(256) void k_transpose384(const float* __restrict__ A,
                                                      float* __restrict__ At) {
    int i = blockIdx.x * 256 + threadIdx.x;          // over 384*128
    if (i < 384 * 128) {
        int r = i >> 7, c = i & 127;
        At[c * 384 + r] = A[i];
    }
}

// ---------------- fused doc FNN + V + GI precompute ----------------
// doc = sigmoid(relu(br @ fnn_W1 + b1) @ fnn_W2 + b2)   (kept in LDS)
// V   = doc @ com_W1[0:128,:]
// GI  = doc @ Wih^T + bih
__global__ __launch_bounds__(256) void k_docvgi(
    const float* __restrict__ br,
    const float* __restrict__ fW1, const float* __restrict__ fb1,
    const float* __restrict__ fW2, const float* __restrict__ fb2,
    const float* __restrict__ comW1,
    const float* __restrict__ WihT, const float* __restrict__ bih,
    float* __restrict__ V, float* __restrict__ GI)
{
    __shared__ float xs[32][FF];
    __shared__ float hs[32][HH];
    __shared__ float ds[32][HH];
    int row0 = blockIdx.x * 32;
    int t = threadIdx.x;
    const float* src = br + (size_t)row0 * FF;
    for (int i = t; i < 32 * FF; i += 256) xs[i / FF][i % FF] = src[i];
    __syncthreads();
    int j = t & 127, rg = t >> 7;
    float acc[16];
    // layer 1: relu(br @ fW1 + b1)
#pragma unroll
    for (int r = 0; r < 16; r++) acc[r] = 0.f;
    for (int k = 0; k < FF; k++) {
        float w = fW1[k * HH + j];
#pragma unroll
        for (int r = 0; r < 16; r++) acc[r] += xs[rg + 2 * r][k] * w;
    }
    {
        float bb = fb1[j];
#pragma unroll
        for (int r = 0; r < 16; r++) hs[rg + 2 * r][j] = fmaxf(acc[r] + bb, 0.f);
    }
    __syncthreads();
    // layer 2: sigmoid(h @ fW2 + b2) -> doc
#pragma unroll
    for (int r = 0; r < 16; r++) acc[r] = 0.f;
    for (int k = 0; k < HH; k++) {
        float w = fW2[k * HH + j];
#pragma unroll
        for (int r = 0; r < 16; r++) acc[r] += hs[rg + 2 * r][k] * w;
    }
    {
        float bb = fb2[j];
#pragma unroll
        for (int r = 0; r < 16; r++)
            ds[rg + 2 * r][j] = 1.f / (1.f + expf(-(acc[r] + bb)));
    }
    __syncthreads();
    // V = doc @ comW1[0:128,:]
#pragma unroll
    for (int r = 0; r < 16; r++) acc[r] = 0.f;
    for (int k = 0; k < HH; k++) {
        float w = comW1[k * HH + j];
#pragma unroll
        for (int r = 0; r < 16; r++) acc[r] += ds[rg + 2 * r][k] * w;
    }
#pragma unroll
    for (int r = 0; r < 16; r++) V[(size_t)(row0 + rg + 2 * r) * HH + j] = acc[r];
    // GI = doc @ WihT + bih  (3 column blocks of 128)
    for (int p = 0; p < 3; p++) {
        int jj = p * HH + j;
#pragma unroll
        for (int r = 0; r < 16; r++) acc[r] = 0.f;
        for (int k = 0; k < HH; k++) {
            float w = WihT[k * 384 + jj];
#pragma unroll
            for (int r = 0; r < 16; r++) acc[r] += ds[rg + 2 * r][k] * w;
        }
        float bb = bih[jj];
#pragma unroll
        for (int r = 0; r < 16; r++)
            GI[(size_t)(row0 + rg + 2 * r) * 384 + jj] = acc[r] + bb;
    }
}

// ---------------- sequential selection scan: one block per batch elem ----------------
__global__ __launch_bounds__(256) void k_scan(
    const float* __restrict__ br,
    const float* __restrict__ cntW1, const float* __restrict__ cntb1,
    const float* __restrict__ cntW2, const float* __restrict__ cntb2,
    const float* __restrict__ comW1, const float* __restrict__ comb1,
    const float* __restrict__ comW2,
    const float* __restrict__ WhhT, const float* __restrict__ gbhh,
    const float* __restrict__ V, const float* __restrict__ GI,
    float* __restrict__ out)
{
    __shared__ float  Vl[SEQ][HH + 1];     // 66 KB, padded vs bank conflicts
    __shared__ float  hS[HH], crS[HH], a1S[HH], uS[HH], scS[SEQ], c2S[HH];
    __shared__ float  mxS[FF], mnS[FF];
    __shared__ double smS[FF];
    __shared__ int    mxiS[FF];
    __shared__ int    maskS[SEQ];
    __shared__ float  pp[2][3][HH];        // stage partials
    __shared__ int    selS;

    int b = blockIdx.x;
    int t = threadIdx.x;
    const float* brB = br + (size_t)b * SEQ * FF;
    const float* Vb  = V  + (size_t)b * SEQ * HH;
    const float* GIb = GI + (size_t)b * SEQ * 3 * HH;

    for (int i = t; i < SEQ * HH; i += 256) { int s = i >> 7, j = i & 127; Vl[s][j] = Vb[i]; }
    if (t < HH)  { hS[t] = 0.f; c2S[t] = comW2[t]; }
    if (t < SEQ) maskS[t] = 1;
    if (t < FF) {
        double sm = 0.0; float mx = -__builtin_huge_valf(); int mi = 0;
        for (int s = 0; s < SEQ; s++) {
            float v = brB[s * FF + t];
            sm += (double)v;
            if (v > mx) { mx = v; mi = s; }
        }
        smS[t] = sm; mxS[t] = mx; mxiS[t] = mi;
    }
    __syncthreads();

    int j = t & 127, hf = t >> 7;

    for (int i = 0; i < SEQ; i++) {
        float cntf = (float)(SEQ - i);
        if (t < FF) mnS[t] = ((float)smS[t]) / cntf;
        __syncthreads();

        // ---- a1 = relu([mx,mn] @ cntW1 + cntb1) ----
        {
            float acc = 0.f;
            if (hf == 0) {
                for (int k = 0; k < FF; k++) acc += mxS[k] * cntW1[k * HH + j];
            } else {
                for (int k = 0; k < FF; k++) acc += mnS[k] * cntW1[(FF + k) * HH + j];
            }
            pp[hf][0][j] = acc;
        }
        __syncthreads();
        if (t < HH) { float v = pp[0][0][t] + pp[1][0][t] + cntb1[t]; a1S[t] = fmaxf(v, 0.f); }
        __syncthreads();

        // ---- cr = sigmoid(a1 @ cntW2 + cntb2) ----
        {
            float acc = 0.f;
            for (int k = hf * 64; k < hf * 64 + 64; k++) acc += a1S[k] * cntW2[k * HH + j];
            pp[hf][0][j] = acc;
        }
        __syncthreads();
        if (t < HH) { float v = pp[0][0][t] + pp[1][0][t] + cntb2[t]; crS[t] = 1.f / (1.f + expf(-v)); }
        __syncthreads();

        // ---- u = cr @ comW1[128:256] + h @ comW1[256:384] + comb1 ----
        {
            const float* srcv = (hf == 0) ? crS : hS;
            const float* W = comW1 + (size_t)(HH + hf * HH) * HH;
            float acc = 0.f;
            for (int k = 0; k < HH; k++) acc += srcv[k] * W[k * HH + j];
            pp[hf][0][j] = acc;
        }
        __syncthreads();
        if (t < HH) uS[t] = pp[0][0][t] + pp[1][0][t] + comb1[t];
        __syncthreads();

        // ---- scores[s] = sum_j c2[j] * relu(V[s][j] + u[j]) ----
        {
            float acc = 0.f;
            for (int k = hf * 64; k < hf * 64 + 64; k++)
                acc += c2S[k] * fmaxf(Vl[j][k] + uS[k], 0.f);
            pp[hf][0][j] = acc;
        }
        __syncthreads();
        if (t < SEQ) scS[t] = pp[0][0][t] + pp[1][0][t];
        __syncthreads();

        // ---- argmax over masked (first-index tie break) ----
        if (t < 64) {
            float v1 = maskS[t]      ? scS[t]      : -__builtin_huge_valf();
            float v2 = maskS[t + 64] ? scS[t + 64] : -__builtin_huge_valf();
            float v; int idx;
            if (v2 > v1) { v = v2; idx = t + 64; } else { v = v1; idx = t; }
            for (int off = 32; off >= 1; off >>= 1) {
                float ov = __shfl_down(v, off);
                int   oi = __shfl_down(idx, off);
                if (ov > v || (ov == v && oi < idx)) { v = ov; idx = oi; }
            }
            if (t == 0) {
                selS = idx;
                maskS[idx] = 0;
                out[(size_t)b * SEQ + idx] = powf(0.9f, (float)i);
            }
        }
        __syncthreads();
        int sel = selS;

        // ---- maintain sums (fp64) and maxes (exact, lazy recompute) ----
        if (t < FF) {
            float rv = brB[sel * FF + t];
            smS[t] -= (double)rv;
            if (sel == mxiS[t] && i < SEQ - 1) {
                float mx = -__builtin_huge_valf(); int mi = 0;
                for (int s = 0; s < SEQ; s++) {
                    if (maskS[s]) { float v = brB[s * FF + t]; if (v > mx) { mx = v; mi = s; } }
                }
                mxS[t] = mx; mxiS[t] = mi;
            }
        }

        // ---- GRU: gh = h @ Whh^T (+bhh), gi = GI[sel] ----
        {
            float ar = 0.f, az = 0.f, an = 0.f;
            for (int k = hf * 64; k < hf * 64 + 64; k++) {
                float hv = hS[k];
                const float* Wr = WhhT + (size_t)k * 384;
                ar += hv * Wr[j];
                az += hv * Wr[HH + j];
                an += hv * Wr[2 * HH + j];
            }
            pp[hf][0][j] = ar; pp[hf][1][j] = az; pp[hf][2][j] = an;
        }
        __syncthreads();
        if (t < HH) {
            const float* gir = GIb + (size_t)sel * 384;
            float ghr = pp[0][0][t] + pp[1][0][t] + gbhh[t];
            float ghz = pp[0][1][t] + pp[1][1][t] + gbhh[HH + t];
            float ghn = pp[0][2][t] + pp[1][2][t] + gbhh[2 * HH + t];
            float r = 1.f / (1.f + expf(-(gir[t] + ghr)));
            float z = 1.f / (1.f + expf(-(gir[HH + t] + ghz)));
            float n = tanhf(gir[2 * HH + t] + r * ghn);
            float hn = (1.f - z) * n + z * hS[t];
            scS[t] = hn;   // reuse as staging
        }
        __syncthreads();
        if (t < HH) hS[t] = scS[t];
        __syncthreads();
    }
}

extern "C" void kernel_launch(void* const* d_in, const int* in_sizes, int n_in,
                              void* d_out, int out_size, void* d_ws, size_t ws_size,
                              hipStream_t stream) {
    (void)in_sizes; (void)n_in; (void)out_size; (void)ws_size;
    const float* br    = (const float*)d_in[0];
    // d_in[1] = label (unused: only ranking is returned)
    const float* fnnW1 = (const float*)d_in[2];
    const float* fnnb1 = (const float*)d_in[3];
    const float* fnnW2 = (const float*)d_in[4];
    const float* fnnb2 = (const float*)d_in[5];
    const float* cntW1 = (const float*)d_in[6];
    const float* cntb1 = (const float*)d_in[7];
    const float* cntW2 = (const float*)d_in[8];
    const float* cntb2 = (const float*)d_in[9];
    const float* comW1 = (const float*)d_in[10];
    const float* comb1 = (const float*)d_in[11];
    const float* comW2 = (const float*)d_in[12];
    // d_in[13] = com_b2 (constant shift, argmax-invariant)
    const float* Wih   = (const float*)d_in[14];
    const float* Whh   = (const float*)d_in[15];
    const float* bih   = (const float*)d_in[16];
    const float* bhh   = (const float*)d_in[17];

    float* ws   = (float*)d_ws;
    float* V    = ws;                         // 512*128*128      =  8,388,608 f
    float* GI   = ws + 8388608;               // 512*128*384      = 25,165,824 f
    float* WihT = ws + 8388608 + 25165824;    // 128*384          =     49,152 f
    float* WhhT = WihT + 49152;               // 128*384          =     49,152 f
    // total ws: 33,652,736 floats = ~134.6 MB

    hipLaunchKernelGGL(k_transpose384, dim3(192), dim3(256), 0, stream, Wih, WihT);
    hipLaunchKernelGGL(k_transpose384, dim3(192), dim3(256), 0, stream, Whh, WhhT);
    hipLaunchKernelGGL(k_docvgi, dim3(2048), dim3(256), 0, stream,
                       br, fnnW1, fnnb1, fnnW2, fnnb2, comW1, WihT, bih, V, GI);
    hipLaunchKernelGGL(k_scan, dim3(BSZ), dim3(256), 0, stream,
                       br, cntW1, cntb1, cntW2, cntb2, comW1, comb1, comW2,
                       WhhT, bhh, V, GI, (float*)d_out);
}